// Round 4
// baseline (1144.009 us; speedup 1.0000x reference)
//
#include <hip/hip_runtime.h>
#include <hip/hip_bf16.h>
#include <stdint.h>

#define NB 512
#define NW 40
#define NE 512
#define NH 512
#define NV 12000
#define G4 2048

typedef unsigned short u16;
typedef unsigned int u32;
typedef unsigned long long u64;
typedef __attribute__((ext_vector_type(8))) short short8;
typedef __attribute__((ext_vector_type(4))) float f32x4;

__device__ __forceinline__ unsigned short f2bf(float f) {
  unsigned int u = __float_as_uint(f);
  u += 0x7FFF + ((u >> 16) & 1);
  return (unsigned short)(u >> 16);
}
__device__ __forceinline__ float bf2f(unsigned short b) {
  return __uint_as_float(((unsigned int)b) << 16);
}
__device__ __forceinline__ float loadIn(const void* p, long i, int bf) {
  return bf ? bf2f(((const u16*)p)[i]) : ((const float*)p)[i];
}
// exp-based tanh: |err| ~1e-7 abs, saturates cleanly (exp->inf => 1).
__device__ __forceinline__ float fast_tanh(float x) {
  float ax = __builtin_fabsf(x);
  float t = 1.f - 2.f * __builtin_amdgcn_rcpf(__expf(ax + ax) + 1.f);
  return __builtin_copysignf(t, x);
}
__device__ __forceinline__ float sigm(float x) {
  return __builtin_amdgcn_rcpf(1.f + __expf(-x));
}

// ---------------- dtype detector ----------------
__global__ void detect_kernel(const u16* p, int* flag) {
  __shared__ int cnt;
  int i = threadIdx.x;
  if (i == 0) cnt = 0;
  __syncthreads();
  unsigned short u = p[2 * (i * 1001)];
  int e = (u >> 7) & 0xFF;
  if (e >= 100 && e <= 126) atomicAdd(&cnt, 1);
  __syncthreads();
  if (i == 0) *flag = (cnt >= 32) ? 1 : 0;
}

// ---------------- tableT = bf16(tanh(lookup_W^T)), (V, E) ----------------
__global__ void table_kernel(const void* lookup, const int* flag, u16* tableT) {
  __shared__ float tile[64][65];
  int bf = *flag;
  int v0 = blockIdx.x * 64, e0 = blockIdx.y * 64;
  int tx = threadIdx.x, ty = threadIdx.y;  // (64,4)
#pragma unroll
  for (int r = 0; r < 16; ++r) {
    int e = r * 4 + ty, v = tx;
    if (v0 + v < NV)
      tile[e][v] = tanhf(loadIn(lookup, (long)(e0 + e) * NV + v0 + v, bf));
  }
  __syncthreads();
#pragma unroll
  for (int r = 0; r < 16; ++r) {
    int v = r * 4 + ty, e = tx;
    if (v0 + v < NV)
      tableT[(long)(v0 + v) * NE + e0 + e] = f2bf(tile[e][v]);
  }
}

// ---------------- emb (W*B, E) bf16, rows tb = t*NB+b ----------------
__global__ void embed_kernel(const int* __restrict__ qv,
                             const u16* __restrict__ tableT,
                             u16* __restrict__ emb) {
  int tid = blockIdx.x * 256 + threadIdx.x;
  int token = tid >> 6;
  int chunk = tid & 63;
  int tt = token / NB, b = token % NB;
  int q = qv[b * NW + tt];
  uint4 val = make_uint4(0u, 0u, 0u, 0u);
  if (q > 0) val = *(const uint4*)(tableT + (long)(q - 1) * NE + chunk * 8);
  *(uint4*)(emb + (long)token * NE + chunk * 8) = val;
}

// ---------------- pack weights: Wc[d] rows = [wih | whh], bf16 ------------
__global__ void pack_kernel(const void* wih0, const void* whh0, const void* b0,
                            const void* wih1, const void* whh1, const void* b1,
                            const int* flag, u16* Wc0, u16* Wc1, float* bsum) {
  const long N0 = 2L * G4 * 1024, N1 = 2L * G4 * 1536;
  long idx = (long)blockIdx.x * 256 + threadIdx.x;
  int bf = *flag;
  if (idx < N0) {
    int d = (int)(idx / (G4 * 1024));
    int rem = (int)(idx % (long)(G4 * 1024));
    int g = rem / 1024, k = rem % 1024;
    float v = (k < 512) ? loadIn(wih0, ((long)d * G4 + g) * 512 + k, bf)
                        : loadIn(whh0, ((long)d * G4 + g) * 512 + (k - 512), bf);
    Wc0[idx] = f2bf(v);
  } else if (idx < N0 + N1) {
    long i2 = idx - N0;
    int d = (int)(i2 / (G4 * 1536));
    int rem = (int)(i2 % (long)(G4 * 1536));
    int g = rem / 1536, k = rem % 1536;
    float v = (k < 1024) ? loadIn(wih1, ((long)d * G4 + g) * 1024 + k, bf)
                         : loadIn(whh1, ((long)d * G4 + g) * 512 + (k - 1024), bf);
    Wc1[i2] = f2bf(v);
  } else if (idx < N0 + N1 + 2L * 2 * G4) {
    long i3 = idx - N0 - N1;  // [layer][d][g]
    int layer = (int)(i3 / (2 * G4));
    int d = (int)((i3 / G4) & 1);
    int g = (int)(i3 % G4);
    const void* bb = layer ? b1 : b0;
    float v = loadIn(bb, (long)d * 2 * G4 + g, bf) +
              loadIn(bb, (long)d * 2 * G4 + G4 + g, bf);
    bsum[i3] = v;
  }
}

// ---------------- zero the barrier (8 KB) ----------------
__global__ void zero_bar(unsigned int* bar) {
  bar[blockIdx.x * 256 + threadIdx.x] = 0u;
}

// ---------------- xg GEMM: xg[t][d][col][b][jn*4+g] = X@Wih^T + bias ------
// 128x128 tile, BK=64, m97-style staging, 4 waves 2x2.
// 1D grid + supertile swizzle (4 bx x 8 by contiguous) so A-tiles
// (4x256KB) and B-tiles (8x256KB) stay cache-resident across reuse.
// R12: xtiled=1 reads X from the tiled h0cat layout [tq][d][cb32][b][16j]
// (k-order identical to the old row-major; only b moved innermost).
__global__ __launch_bounds__(256, 2) void xg_gemm(
    const u16* __restrict__ X, int Kx, int Kfull, int xtiled,
    const u16* __restrict__ Wc, const float* __restrict__ bsumL,
    u16* __restrict__ xg) {
  __shared__ __align__(16) char lds[32768];  // A 16K + B 16K
  const int tid = threadIdx.x;
  const int lane = tid & 63, wv = tid >> 6;
  const int wm = wv & 1, wn = wv >> 1;
  const int col = lane & 15, quad = lane >> 4;
  const int s = blockIdx.x >> 5, w = blockIdx.x & 31;
  const int bx = (s % 40) * 4 + (w & 3);
  const int by = (s / 40) * 8 + (w >> 2);
  const int tb0 = bx * 128;
  const int d = by >> 4, colb = by & 15, j0 = colb * 32;

  f32x4 zero = {0.f, 0.f, 0.f, 0.f};
  f32x4 acc[4][4];
#pragma unroll
  for (int i = 0; i < 4; ++i)
#pragma unroll
    for (int j = 0; j < 4; ++j) acc[i][j] = zero;

  const int iters = Kx >> 6;
  for (int it = 0; it < iters; ++it) {
    int k0 = it << 6;
#pragma unroll
    for (int p = 0; p < 8; ++p) {
      int c = p * 256 + tid;  // [0,2048)
      const u16* gsrc;
      if (c < 1024) {  // A rows 0..127
        int r = c >> 3, sl = c & 7;
        int kk = k0 + ((sl * 8) ^ ((r & 7) << 3));
        int tb = tb0 + r;
        if (xtiled) {
          // X = [tq][d*32+cb = kk>>4][b 512][16 jj]
          gsrc = X + ((long)(tb >> 9) * 64 + (kk >> 4)) * 8192 +
                 (long)(tb & 511) * 16 + (kk & 15);
        } else {
          gsrc = X + (long)tb * Kx + kk;
        }
      } else {
        int cb = c - 1024;
        int r = cb >> 3, sl = cb & 7;
        int kk = k0 + ((sl * 8) ^ ((r & 7) << 3));
        int grow = (r >> 5) * 512 + j0 + (r & 31);
        gsrc = Wc + ((long)d * G4 + grow) * Kfull + kk;
      }
      __builtin_amdgcn_global_load_lds(
          (const __attribute__((address_space(1))) void*)(const void*)gsrc,
          (__attribute__((address_space(3))) void*)(lds + p * 4096 + wv * 1024),
          16, 0, 0);
    }
    __syncthreads();
    const u16* As = (const u16*)lds;
    const u16* Bs = (const u16*)(lds + 16384);
#pragma unroll
    for (int ks = 0; ks < 2; ++ks) {
      short8 afr[4], bfr[4];
#pragma unroll
      for (int mf = 0; mf < 4; ++mf) {
        int rm = wm * 64 + mf * 16 + col;
        int sl = (ks * 32 + quad * 8) ^ ((rm & 7) << 3);
        afr[mf] = *(const short8*)(As + rm * 64 + sl);
      }
#pragma unroll
      for (int nf = 0; nf < 4; ++nf) {
        int br = wn * 64 + nf * 16 + col;
        int sl = (ks * 32 + quad * 8) ^ ((br & 7) << 3);
        bfr[nf] = *(const short8*)(Bs + br * 64 + sl);
      }
#pragma unroll
      for (int mf = 0; mf < 4; ++mf)
#pragma unroll
        for (int nf = 0; nf < 4; ++nf)
          acc[mf][nf] = __builtin_amdgcn_mfma_f32_16x16x32_bf16(
              afr[mf], bfr[nf], acc[mf][nf], 0, 0, 0);
    }
    __syncthreads();
  }

  float bias[4];
#pragma unroll
  for (int nf = 0; nf < 4; ++nf) {
    int n = wn * 64 + nf * 16 + col;
    bias[nf] = bsumL[d * G4 + (n >> 5) * 512 + j0 + (n & 31)];
  }
#pragma unroll
  for (int mf = 0; mf < 4; ++mf)
#pragma unroll
    for (int nf = 0; nf < 4; ++nf) {
      int n = wn * 64 + nf * 16 + col;
      int g = n >> 5, jn = n & 31;
#pragma unroll
      for (int r = 0; r < 4; ++r) {
        int m = wm * 64 + mf * 16 + quad * 4 + r;
        int tb = tb0 + m, t = tb >> 9, b = tb & 511;
        long oi = ((((long)t * 2 + d) * 16 + colb) * 512 + b) * 128 + jn * 4 + g;
        xg[oi] = f2bf(acc[mf][nf][r] + bias[nf]);
      }
    }
}

// ---------------- persistent bidirectional LSTM recurrence ----------------
// R12: occupancy doubler. R8-R11 all land at 8-9us/step with identical MFMA
// cycles; the invariant was 160KB LDS -> 1 block/CU -> 1 wave/SIMD: every
// LLC latency in a wave's chain is a bare SIMD idle. Here:
//  * 512 blocks: (mi 8) x (d 2) x (cb 32 col-slices of 16 cols).
//  * Whh slice 64 rows x 512 k = 64 KB; wave-private stage 2x2KB x4 = 16 KB
//    -> 80 KB/block exactly -> 2 blocks/CU -> 2 waves/SIMD.
//  * wave w owns rows m0+w*16..+16, computes all 4 gates x 16 cols
//    (64 MFMA/step); R11's wave-independent flag protocol, clique = 32
//    writers (waves with same w across cb'=0..31), 32-lane ballot poll.
//  * stage: 8 chunks of 64k (2 KB, 2 gload_lds), 2-deep counted vmcnt.
//  * h0cat TILED layout [tq][d][cb][b 512][16 jj]: each wave stores full
//    64B lines (R10 lesson); k-order is unchanged (d*512+cb*16+jj), so
//    xg_gemm layer-1 only changes its A-address math (xtiled=1).
__global__ __launch_bounds__(256, 2) void lstm_pers(
    const u16* __restrict__ xg, const u16* __restrict__ Wc, int Kfull, int Kx,
    u16* __restrict__ hbuf, u16* __restrict__ h0cat, void* __restrict__ outp,
    const int* __restrict__ qlen, const int* __restrict__ flag,
    unsigned int* bar, int layer) {
  __shared__ __align__(16) char lds[81920];  // [Whh 64K][4 waves x 2x2K]
  const int tid = threadIdx.x;
  const int lane = tid & 63, wv = tid >> 6;
  const int col = lane & 15, quad = lane >> 4;
  const int l = blockIdx.x;
  const int cb = l & 31;   // 32 column slices of 16
  const int gid = l >> 5;  // (mi,d) clique id: d = gid&1, mi = gid>>1
  const int d = gid & 1, mi = gid >> 1;
  const int j0 = cb * 16;
  const int m0 = mi * 64;
  const int r0 = wv * 16;  // wave's batch-row offset within m0

  // ---- preload Whh slice [64 rows = [g 4][jj 16]][512 k], swizzled ----
#pragma unroll
  for (int p = 0; p < 16; ++p) {
    int c = p * 256 + tid;
    int row = c >> 6, rem = c & 63;
    int kc = rem >> 3, sl = rem & 7;
    int grow = (row >> 4) * 512 + j0 + (row & 15);
    int gk = Kx + kc * 64 + ((sl * 8) ^ ((row & 7) << 3));
    const u16* gsrc = Wc + ((long)d * G4 + grow) * Kfull + gk;
    __builtin_amdgcn_global_load_lds(
        (const __attribute__((address_space(1))) void*)(const void*)gsrc,
        (__attribute__((address_space(3))) void*)(lds + p * 4096 + wv * 1024),
        16, 0, 0);
  }
  const u16* Bs = (const u16*)lds;
  char* wbuf = lds + 65536 + wv * 4096;  // wave-private 2 x 2 KB stage
  u16* packb = (u16*)wbuf;  // 512 B h-pack, aliases buf0 (in-order DS ops)

  float creg[4];
#pragma unroll
  for (int r = 0; r < 4; ++r) creg[r] = 0.f;
  const int isbf = *flag;
  f32x4 zero = {0.f, 0.f, 0.f, 0.f};

  __syncthreads();  // Whh resident (the ONLY block barrier in this kernel)

#pragma unroll 1
  for (int t = 0; t < NW; ++t) {
    const int tq = d ? (NW - 1 - t) : t;

    // xg prefetch (independent of the wait): row = r0+quad*4+r, 16 cols
    ushort4 xgv[4];
    const u16* xgt =
        xg + ((((long)tq * 2 + d) * 16 + (cb >> 1)) * 512 + m0 + r0) * 128;
#pragma unroll
    for (int r = 0; r < 4; ++r)
      xgv[r] =
          *(const ushort4*)(xgt + (quad * 4 + r) * 128 + ((cb & 1) * 16 + col) * 4);
    __builtin_amdgcn_sched_barrier(0);

    f32x4 acc[4];
#pragma unroll
    for (int g = 0; g < 4; ++g) acc[g] = zero;

    if (t > 0) {
      // ---- poll the 32 writer waves (same w, cb' 0..31) of rows r0 ----
      {
        u32* sp = bar + ((gid * 4 + wv) << 5) + (lane & 31);
        while (__ballot((int)(__hip_atomic_load(sp, __ATOMIC_RELAXED,
                                                __HIP_MEMORY_SCOPE_AGENT) <
                              (u32)t)))
          __builtin_amdgcn_s_sleep(1);
      }
      __builtin_amdgcn_sched_barrier(0);

      const u16* hp = hbuf + ((t - 1) & 1) * (2L * NB * NH) +
                      ((long)d * NB + m0 + r0) * NH;
      // wave-private stage: 16 rows x 64 k = 2 KB per chunk, SC1 (LLC)
      auto stage = [&](int it) {
        char* dst = wbuf + (it & 1) * 2048;
#pragma unroll
        for (int i = 0; i < 2; ++i) {
          int c = i * 64 + lane;
          int row = c >> 3, slot = c & 7;
          int kk = it * 64 + ((slot * 8) ^ ((row & 7) << 3));
          const u16* gsrc = hp + (long)row * NH + kk;
          __builtin_amdgcn_global_load_lds(
              (const __attribute__((address_space(1))) void*)(const void*)gsrc,
              (__attribute__((address_space(3))) void*)(dst + i * 1024), 16, 0,
              16 /* SC1: agent-coherent read from LLC */);
        }
      };
      stage(0);
      stage(1);
#pragma unroll 1
      for (int it = 0; it < 8; ++it) {
        // chunk `it` ready: next chunk's 2 insts may stay outstanding
        if (it < 7)
          asm volatile("s_waitcnt vmcnt(2)" ::: "memory");
        else
          asm volatile("s_waitcnt vmcnt(0)" ::: "memory");
        const u16* As = (const u16*)(wbuf + (it & 1) * 2048);
        short8 afr[2];
#pragma unroll
        for (int ks = 0; ks < 2; ++ks) {
          int ksub = ks * 32 + quad * 8;
          afr[ks] = *(const short8*)(As + col * 64 + (ksub ^ ((col & 7) << 3)));
        }
        if (it < 6) {
          // buf (it&1) reads retired before re-staging into it
          asm volatile("s_waitcnt lgkmcnt(0)" ::: "memory");
          __builtin_amdgcn_sched_barrier(0);
          stage(it + 2);
        }
#pragma unroll
        for (int ks = 0; ks < 2; ++ks) {
          const int kc = it * 64 + ks * 32 + quad * 8;
#pragma unroll
          for (int nf = 0; nf < 4; ++nf) {
            int br = nf * 16 + col;
            int slb = (kc & 63) ^ ((br & 7) << 3);
            short8 bfr = *(const short8*)(Bs + br * 512 + (kc & ~63) + slb);
            acc[nf] = __builtin_amdgcn_mfma_f32_16x16x32_bf16(afr[ks], bfr,
                                                              acc[nf], 0, 0, 0);
          }
        }
      }
    }

    // ---- wave-local cell update; pack h into wave's 512 B LDS ----
#pragma unroll
    for (int r = 0; r < 4; ++r) {
      const u16* xv = (const u16*)&xgv[r];
      float gi = acc[0][r] + bf2f(xv[0]);
      float gf = acc[1][r] + bf2f(xv[1]);
      float gg = acc[2][r] + bf2f(xv[2]);
      float go = acc[3][r] + bf2f(xv[3]);
      float si = sigm(gi);
      float sf = sigm(gf);
      float so = sigm(go);
      float cn = sf * creg[r] + si * fast_tanh(gg);
      float h = so * fast_tanh(cn);
      creg[r] = cn;
      packb[(quad * 4 + r) * 16 + col] = f2bf(h);
      // fp32 output path: store full-precision h directly (rare rows)
      if (layer == 1 && !isbf) {
        int bg = m0 + r0 + quad * 4 + r;
        if (qlen[bg] - 1 == tq)
          ((float*)outp)[(long)bg * (2 * NH) + d * NH + j0 + col] = h;
      }
    }

    // ---- wave-local coalesced stores from the pack (32 B per row) ----
    const int srow = lane >> 2, part = lane & 3;
    u64 v0 = *(const u64*)(packb + srow * 16 + part * 4);
    u16* hnxt = hbuf + (t & 1) * (2L * NB * NH);
    __hip_atomic_store(
        (u64*)(hnxt + ((long)d * NB + m0 + r0 + srow) * NH + j0 + part * 4), v0,
        __ATOMIC_RELAXED, __HIP_MEMORY_SCOPE_AGENT);

    // ---- per-wave drain, then signal own flag slot ----
    if (t < NW - 1) {
      asm volatile("s_waitcnt vmcnt(0)" ::: "memory");
      if (lane == 0)
        __hip_atomic_store(bar + ((gid * 4 + wv) << 5) + cb, (u32)(t + 1),
                           __ATOMIC_RELAXED, __HIP_MEMORY_SCOPE_AGENT);
    }

    // ---- deferred HBM stores (off the signal's critical path) ----
    if (layer == 0) {
      // tiled h0cat: [tq][d*32+cb][b 512][16 jj] -- full 64B lines
      u16* dst = h0cat + ((((long)tq * 2 + d) * 32 + cb) * 512 +
                          (m0 + r0 + srow)) * 16 + part * 4;
      *(u64*)dst = v0;
    } else if (isbf) {
      int bg = m0 + r0 + srow;
      if (qlen[bg] - 1 == tq) {
        u16* dst = (u16*)outp + (long)bg * (2 * NH) + d * NH + j0 + part * 4;
        *(u64*)dst = v0;
      }
    }
    __builtin_amdgcn_sched_barrier(0);
  }
}

extern "C" void kernel_launch(void* const* d_in, const int* in_sizes, int n_in,
                              void* d_out, int out_size, void* d_ws,
                              size_t ws_size, hipStream_t stream) {
  const int* qv = (const int*)d_in[0];
  const int* ql = (const int*)d_in[1];
  const void* lookup = d_in[2];
  const void* wih0 = d_in[3];
  const void* whh0 = d_in[4];
  const void* b0 = d_in[5];
  const void* wih1 = d_in[6];
  const void* whh1 = d_in[7];
  const void* b1 = d_in[8];

  char* ws = (char*)d_ws;
  size_t off = 0;
  int* flag = (int*)ws;                 off += 256;
  unsigned int* bar = (unsigned int*)(ws + off); off += 8192;
  float* bsum = (float*)(ws + off);     off += 2L * 2 * G4 * 4;        // 32 KB
  u16* Wc0 = (u16*)(ws + off);          off += 2L * G4 * 1024 * 2;     // 8 MB
  u16* Wc1 = (u16*)(ws + off);          off += 2L * G4 * 1536 * 2;     // 12 MB
  u16* hbuf = (u16*)(ws + off);         off += 2L * 2 * NB * NH * 2;   // 2 MB
  u16* h0cat = (u16*)(ws + off);        off += (size_t)NW * NB * 2 * NH * 2; // 40 MB
  u16* emb = (u16*)(ws + off);          off += (size_t)NW * NB * NE * 2;     // 20 MB
  u16* xg = (u16*)(ws + off);           off += (size_t)NW * 2 * 16 * 512 * 128 * 2; // 168 MB
  u16* tableT = h0cat;  // tableT (12.3 MB) aliases h0cat: dead before layer0

  detect_kernel<<<1, 64, 0, stream>>>((const u16*)lookup, flag);
  table_kernel<<<dim3(188, 8), dim3(64, 4), 0, stream>>>(lookup, flag, tableT);
  {
    long total = 2L * G4 * 1024 + 2L * G4 * 1536 + 2L * 2 * G4;
    int blocks = (int)((total + 255) / 256);
    pack_kernel<<<blocks, 256, 0, stream>>>(wih0, whh0, b0, wih1, whh1, b1,
                                            flag, Wc0, Wc1, bsum);
  }
  embed_kernel<<<NW * NB / 4, 256, 0, stream>>>(qv, tableT, emb);

  // layer 0
  xg_gemm<<<5120, 256, 0, stream>>>(emb, 512, 1024, 0, Wc0, bsum, xg);
  zero_bar<<<8, 256, 0, stream>>>(bar);
  lstm_pers<<<512, 256, 0, stream>>>(xg, Wc0, 1024, 512, hbuf, h0cat, d_out,
                                     ql, flag, bar, 0);
  // layer 1
  xg_gemm<<<5120, 256, 0, stream>>>(h0cat, 1024, 1536, 1, Wc1, bsum + 2 * G4,
                                    xg);
  zero_bar<<<8, 256, 0, stream>>>(bar);
  lstm_pers<<<512, 256, 0, stream>>>(xg, Wc1, 1536, 1024, hbuf, h0cat, d_out,
                                     ql, flag, bar, 1);
}